// Round 12
// baseline (340.996 us; speedup 1.0000x reference)
//
#include <hip/hip_runtime.h>
#include <math.h>

// MADE autoregressive sampler, v22: one block per CU, halved LDS-pipe load.
// B=8192, D=64, CTX=256, H=512. Units sorted by degree (mh = h%63+1).
// Falsified: occupancy (v15), L2-amortization (v16 -3%), barrier count
// (v17/v18), chain-sync (v20), VMEM exposure (v21 prefetch null). New model:
// per-CU LDS issue pipe. v16: 8 waves/CU x 49 broadcast ds_read_b128/step =
// 392 issues x ~8-12cy = 3100-4700 cy/step -- the structure-invariant wall
// (v14: 29x12=350 same dur; v15: 23x24=550 -> 1.7x dur. Consistent.)
// v22: grid 256 = 1 block/CU, Rn=32, 256 thr / 4 waves (1/SIMD). Thread owns
// 4 units x 16 rows (row-half rh = t>>7) for FA/MID, 2 cols x 8 rows (wave w)
// for D/E. Per-wave LDS reads: zcur 4 + MID 36 + D 18 = 58; per-CU = 232
// (-41% vs v16). Total VALU/CU unchanged; per-wave VALU doubles to fill
// 1-wave/SIMD issue. VGPR ~260-320 under the 512 cap of launch_bounds(256,1).
// v19's 1-wave/SIMD failure was bank conflicts (4.7e7); here all LDS reads
// are wave-uniform broadcasts (conflict-free). Spill tripwire: WRITE_SIZE
// must stay 6144 KB.
// Masks/sequencing identical to v16: E(col S) -> bar1 -> FA(+z_S, publish
// h1 at finalize) -> bar2 -> MID(+h1_S, publish h2) -> bar3 -> D(+Wo.h2_S).
// Slot-8 weights prep-zeroed kill stale 9th-lane reads (8-wide groups).

typedef float f2 __attribute__((ext_vector_type(2)));

#define Bn 8192
#define Dn 64
#define CTXn 256
#define Hn 512
#define Rn 32
#define BD (Bn * Dn)

#define WQ_SZ  (64 * 512 * 12)   // 393216
#define WOQ_SZ (64 * 64 * 20)    //  81920
#define WCT_SZ (512 * 256)       // 131072

// lgkm-only block barrier: drains LDS ops, leaves global loads in flight.
#define BARRIER() do {                                      \
    asm volatile("s_waitcnt lgkmcnt(0)" ::: "memory");      \
    __builtin_amdgcn_s_barrier();                           \
    asm volatile("" ::: "memory");                          \
  } while (0)

// sorted index p -> original hidden unit h, and its degree k.
__device__ __forceinline__ int perm_of(int p, int* degout) {
  int k, t;
  if (p < 72) { k = p / 9 + 1; t = p - (k - 1) * 9; }
  else        { int pp = p - 72; k = pp / 8 + 9; t = pp - (k - 9) * 8; }
  *degout = k;
  return (k - 1) + 63 * t;
}
// original unit h -> sorted index q.
__device__ __forceinline__ int inv_perm(int h) {
  int i = h % 63;
  int t = h / 63;
  int base = (i < 9) ? 9 * i : 72 + 8 * (i - 8);
  return base + t;
}

// ---------------- prep -------------------------------------------------------
// R0 W2-scan:  W2[hq][hp], hp=63e+i -> Wq[i][qs(hq)][e]
// R1 W1-scan:  W1[hq][i]            -> Wq[i][qs(hq)][9]   (FA weight slot)
// R2 Wo-scan:  Wo[o][hp], hp=63p+i  -> Woq[i][o&63][(o>>6)*10+p]
// R3 Wc-scan:  Wc[hq][cc]           -> WcT2[qs(hq)][cc]   (unit-major)
// R4 zero:     Wq[i>=8][q][8], Woq[i>=8][j][8|18]
// R5 biases:   b1p/b2p
#define R0e 262144
#define R1e (R0e + 32768)
#define R2e (R1e + 65536)
#define R3e (R2e + 131072)
#define R4e (R3e + 35840)
#define R5e (R4e + 1024)
__global__ void prep_kernel(const float* __restrict__ W1, const float* __restrict__ Wc,
                            const float* __restrict__ W2, const float* __restrict__ Wo,
                            const float* __restrict__ b1, const float* __restrict__ b2,
                            float* __restrict__ Wq, float* __restrict__ Woq,
                            float* __restrict__ WcT2, float* __restrict__ b1p,
                            float* __restrict__ b2p) {
  int idx = blockIdx.x * 256 + threadIdx.x;
  if (idx < R0e) {                      // W2 scan
    int hq = idx >> 9, hp = idx & 511;
    int i = hp % 63, e = hp / 63;
    Wq[i * 6144 + inv_perm(hq) * 12 + e] = W2[idx];
  } else if (idx < R1e) {               // W1 -> Wq slot 9
    int jj = idx - R0e;
    int hq = jj >> 6, i = jj & 63;
    Wq[i * 6144 + inv_perm(hq) * 12 + 9] = W1[jj];
  } else if (idx < R2e) {               // Wo scan
    int jj = idx - R1e;
    int o = jj >> 9, hp = jj & 511;
    int i = hp % 63, p = hp / 63;
    int j = o & 63, half = o >> 6;
    Woq[i * 1280 + j * 20 + half * 10 + p] = Wo[jj];
  } else if (idx < R3e) {               // Wc scan -> unit-major
    int jj = idx - R2e;
    int hq = jj >> 8, cc = jj & 255;
    WcT2[inv_perm(hq) * 256 + cc] = Wc[jj];
  } else if (idx < R4e) {               // zero 9th slots for 8-wide groups
    int z = idx - R3e;
    if (z < 28672) {                    // Wq[i][q][8], i = 8..63
      int i = 8 + (z >> 9), q = z & 511;
      Wq[i * 6144 + q * 12 + 8] = 0.f;
    } else {                            // Woq[i][j][8 or 18], i = 8..63
      int z2 = z - 28672;
      int i = 8 + (z2 >> 7), r = z2 & 127;
      int j = r & 63, half = r >> 6;
      Woq[i * 1280 + j * 20 + half * 10 + 8] = 0.f;
    }
  } else if (idx < R5e) {               // permuted biases
    int z = idx - R4e;
    if (z < 512) {
      int dq; int hq = perm_of(z, &dq);
      b1p[z] = b1[hq];
    } else {
      int q = z - 512;
      int dq; int hq = perm_of(q, &dq);
      b2p[q] = b2[hq];
    }
  }
}

// ---------------- main fused kernel ------------------------------------------
// 256 threads = 4 waves, grid 256 (1 block/CU). Rn=32 rows/block.
// FA/MID: rh = t>>7 (rows 16rh..16rh+15); thread owns units q_k = (t&127)+128k.
// D/E:    wave w = t>>6 (rows 8w..8w+7); cols (l, l+64), l = t&63.
__global__ __launch_bounds__(256, 1)
void made_v22_kernel(
    const float* __restrict__ context, const float* __restrict__ WcT2,
    const float* __restrict__ b1p, const float* __restrict__ Wq,
    const float* __restrict__ Woq, const float* __restrict__ b2p,
    const float* __restrict__ bo, const float* __restrict__ eps,
    float* __restrict__ out) {
  __shared__ __align__(16) float ctxR[Rn][264];
  __shared__ __align__(16) float zcur[32];
  __shared__ __align__(16) float h1g[9][32];
  __shared__ __align__(16) float h2g[9][32];

  int t = threadIdx.x;
  int w = t >> 6, l = t & 63;
  int rh = t >> 7, tq = t & 127;
  int b0 = blockIdx.x * Rn;
  int fr = 16 * rh;                    // local first row of FA/MID half
  int dr0 = b0 + 8 * w;                // first global row for D/E

  int qk[4], gk[4];
  #pragma unroll
  for (int k = 0; k < 4; ++k) {
    qk[k] = tq + 128 * k;
    gk[k] = (qk[k] < 72) ? qk[k] / 9 : (qk[k] - 72) / 8 + 8;
  }

  // ---- stage ctx (32 rows x 256) ----
  #pragma unroll
  for (int r = 0; r < Rn; ++r)
    ctxR[r][t] = context[(b0 + r) * CTXn + t];
  BARRIER();

  // ---- ctx GEMM: a1[k][rr] = rows (fr+2rr, fr+2rr+1) preact for unit qk ----
  f2 a1[4][8];
  #pragma unroll
  for (int k = 0; k < 4; ++k) {
    float b = b1p[qk[k]];
    #pragma unroll
    for (int rr = 0; rr < 8; ++rr) a1[k][rr] = (f2){b, b};
  }
  {
    #pragma clang loop unroll(disable)
    for (int c4 = 0; c4 < 64; ++c4) {
      float4 xr[16];
      #pragma unroll
      for (int r = 0; r < 16; ++r)
        xr[r] = *(const float4*)&ctxR[fr + r][4 * c4];
      float4 wv[4];
      #pragma unroll
      for (int k = 0; k < 4; ++k)
        wv[k] = *(const float4*)&WcT2[(size_t)qk[k] * 256 + 4 * c4];
      #pragma unroll
      for (int cc = 0; cc < 4; ++cc) {
        f2 x[8];
        #pragma unroll
        for (int rr = 0; rr < 8; ++rr) {
          float xa = (cc == 0) ? xr[2 * rr].x : (cc == 1) ? xr[2 * rr].y
                   : (cc == 2) ? xr[2 * rr].z : xr[2 * rr].w;
          float xb = (cc == 0) ? xr[2 * rr + 1].x : (cc == 1) ? xr[2 * rr + 1].y
                   : (cc == 2) ? xr[2 * rr + 1].z : xr[2 * rr + 1].w;
          x[rr] = (f2){xa, xb};
        }
        #pragma unroll
        for (int k = 0; k < 4; ++k) {
          float ws = (cc == 0) ? wv[k].x : (cc == 1) ? wv[k].y
                   : (cc == 2) ? wv[k].z : wv[k].w;
          f2 ww = (f2){ws, ws};
          #pragma unroll
          for (int rr = 0; rr < 8; ++rr) a1[k][rr] += ww * x[rr];
        }
      }
    }
  }

  f2 a2[4][8];
  #pragma unroll
  for (int k = 0; k < 4; ++k) {
    float b = b2p[qk[k]];
    #pragma unroll
    for (int rr = 0; rr < 8; ++rr) a2[k][rr] = (f2){b, b};
  }
  f2 ocA[4], ocB[4];
  {
    float ba = bo[l], bb = bo[l + 64];
    #pragma unroll
    for (int jj = 0; jj < 4; ++jj) { ocA[jj] = (f2){ba, ba}; ocB[jj] = (f2){bb, bb}; }
  }
  f2 ez[4];
  #pragma unroll
  for (int jj = 0; jj < 4; ++jj)
    ez[jj] = (f2){eps[(dr0 + 2 * jj) * Dn + l], eps[(dr0 + 2 * jj + 1) * Dn + l]};

  // ---- step loop: 3 barriers/step (v16 sequencing) ----
  #pragma clang loop unroll(disable)
  for (int i = 0; i < Dn; ++i) {
    bool fin = (i < 63);

    // E: lane l==i of each wave finalizes cols (i, i+64) for rows 8w..8w+7
    if (l == i) {
      float4 zq0, zq1;
      #pragma unroll
      for (int jj = 0; jj < 4; ++jj) {
        f2 pre = ocB[jj];
        float sx = fmaxf(pre.x, 0.f) + __logf(1.f + __expf(-fabsf(pre.x)));
        float sy = fmaxf(pre.y, 0.f) + __logf(1.f + __expf(-fabsf(pre.y)));
        f2 sc = (f2){sx, sy};
        f2 z = ocA[jj] + sc * ez[jj];
        out[(dr0 + 2 * jj) * Dn + i] = z.x;
        out[(dr0 + 2 * jj + 1) * Dn + i] = z.y;
        out[BD + (dr0 + 2 * jj) * Dn + i] = ocA[jj].x;
        out[BD + (dr0 + 2 * jj + 1) * Dn + i] = ocA[jj].y;
        out[2 * BD + (dr0 + 2 * jj) * Dn + i] = sc.x;
        out[2 * BD + (dr0 + 2 * jj + 1) * Dn + i] = sc.y;
        if (jj == 0) { zq0.x = z.x; zq0.y = z.y; }
        if (jj == 1) { zq0.z = z.x; zq0.w = z.y; }
        if (jj == 2) { zq1.x = z.x; zq1.y = z.y; }
        if (jj == 3) { zq1.z = z.x; zq1.w = z.y; }
      }
      *(float4*)&zcur[8 * w] = zq0;
      *(float4*)&zcur[8 * w + 4] = zq1;
    }
    BARRIER();                                   // bar1: z_i published

    int sb = (i < 8) ? 9 * i : 8 * i + 8;
    float4 wq[4][3];
    if (fin) {
      // Wq[i] loads: 4 units x 3 b128 (slot 9 = [2].y is the FA weight)
      #pragma unroll
      for (int k = 0; k < 4; ++k) {
        const float4* pq =
            (const float4*)(Wq + (size_t)i * 6144 + (size_t)qk[k] * 12);
        wq[k][0] = pq[0]; wq[k][1] = pq[1]; wq[k][2] = pq[2];
      }
      // FA: a1 += W1[:,i] * z_i  (rows fr..fr+15)
      float4 z0 = *(const float4*)&zcur[fr];
      float4 z1 = *(const float4*)&zcur[fr + 4];
      float4 z2 = *(const float4*)&zcur[fr + 8];
      float4 z3 = *(const float4*)&zcur[fr + 12];
      f2 zz[8] = {(f2){z0.x, z0.y}, (f2){z0.z, z0.w},
                  (f2){z1.x, z1.y}, (f2){z1.z, z1.w},
                  (f2){z2.x, z2.y}, (f2){z2.z, z2.w},
                  (f2){z3.x, z3.y}, (f2){z3.z, z3.w}};
      #pragma unroll
      for (int k = 0; k < 4; ++k) {
        f2 ww = (f2){wq[k][2].y, wq[k][2].y};
        #pragma unroll
        for (int rr = 0; rr < 8; ++rr) a1[k][rr] += ww * zz[rr];
      }
      // h1 finalize (unit qk hits its group step; at most one k per step)
      #pragma unroll
      for (int k = 0; k < 4; ++k) {
        if (gk[k] == i) {
          int pp = qk[k] - sb;
          #pragma unroll
          for (int s = 0; s < 4; ++s) {
            float4 h = {fmaxf(a1[k][2 * s].x, 0.f), fmaxf(a1[k][2 * s].y, 0.f),
                        fmaxf(a1[k][2 * s + 1].x, 0.f), fmaxf(a1[k][2 * s + 1].y, 0.f)};
            *(float4*)&h1g[pp][fr + 4 * s] = h;
          }
        }
      }
    }
    BARRIER();                                   // bar2: h1_i published

    float4 wo0, wo1, wo2, wo3, wo4;
    if (fin) {
      // Woq loads for D (latency hidden under MID)
      const float4* wo = (const float4*)(Woq + (size_t)i * 1280 + (size_t)l * 20);
      wo0 = wo[0]; wo1 = wo[1]; wo2 = wo[2]; wo3 = wo[3]; wo4 = wo[4];

      // MID: a2 += W2[:, group i] . h1_i  (slot-8 zeroed for i>=8)
      #pragma unroll
      for (int p = 0; p < 9; ++p) {
        float4 ha = *(const float4*)&h1g[p][fr];
        float4 hb = *(const float4*)&h1g[p][fr + 4];
        float4 hc = *(const float4*)&h1g[p][fr + 8];
        float4 hd = *(const float4*)&h1g[p][fr + 12];
        f2 h[8] = {(f2){ha.x, ha.y}, (f2){ha.z, ha.w},
                   (f2){hb.x, hb.y}, (f2){hb.z, hb.w},
                   (f2){hc.x, hc.y}, (f2){hc.z, hc.w},
                   (f2){hd.x, hd.y}, (f2){hd.z, hd.w}};
        #pragma unroll
        for (int k = 0; k < 4; ++k) {
          float ws = (p == 0) ? wq[k][0].x : (p == 1) ? wq[k][0].y
                   : (p == 2) ? wq[k][0].z : (p == 3) ? wq[k][0].w
                   : (p == 4) ? wq[k][1].x : (p == 5) ? wq[k][1].y
                   : (p == 6) ? wq[k][1].z : (p == 7) ? wq[k][1].w
                              : wq[k][2].x;
          f2 ww = (f2){ws, ws};
          #pragma unroll
          for (int rr = 0; rr < 8; ++rr) a2[k][rr] += ww * h[rr];
        }
      }
      // h2 finalize
      #pragma unroll
      for (int k = 0; k < 4; ++k) {
        if (gk[k] == i) {
          int pp = qk[k] - sb;
          #pragma unroll
          for (int s = 0; s < 4; ++s) {
            float4 h = {fmaxf(a2[k][2 * s].x, 0.f), fmaxf(a2[k][2 * s].y, 0.f),
                        fmaxf(a2[k][2 * s + 1].x, 0.f), fmaxf(a2[k][2 * s + 1].y, 0.f)};
            *(float4*)&h2g[pp][fr + 4 * s] = h;
          }
        }
      }
    }
    BARRIER();                                   // bar3: h2_i published

    // D: oc += Wo[:, group i] . h2_i  (rows 8w..8w+7; slot-8 zeroed)
    if (fin) {
      float wa[9] = {wo0.x, wo0.y, wo0.z, wo0.w, wo1.x, wo1.y, wo1.z, wo1.w, wo2.x};
      float wb[9] = {wo2.z, wo2.w, wo3.x, wo3.y, wo3.z, wo3.w, wo4.x, wo4.y, wo4.z};
      #pragma unroll
      for (int p = 0; p < 9; ++p) {
        float4 h0 = *(const float4*)&h2g[p][8 * w];       // wave-uniform addr
        float4 h1_ = *(const float4*)&h2g[p][8 * w + 4];
        f2 ha = (f2){h0.x, h0.y}, hbp = (f2){h0.z, h0.w};
        f2 hcp = (f2){h1_.x, h1_.y}, hdp = (f2){h1_.z, h1_.w};
        f2 va = (f2){wa[p], wa[p]}, vb = (f2){wb[p], wb[p]};
        ocA[0] += va * ha; ocA[1] += va * hbp;
        ocA[2] += va * hcp; ocA[3] += va * hdp;
        ocB[0] += vb * ha; ocB[1] += vb * hbp;
        ocB[2] += vb * hcp; ocB[3] += vb * hdp;
      }
    }
  }
  // outputs fully streamed in E; no epilogue
}

extern "C" void kernel_launch(void* const* d_in, const int* in_sizes, int n_in,
                              void* d_out, int out_size, void* d_ws, size_t ws_size,
                              hipStream_t stream) {
  const float* context = (const float*)d_in[0];
  const float* eps     = (const float*)d_in[1];
  const float* W1      = (const float*)d_in[2];
  const float* b1      = (const float*)d_in[3];
  const float* Wc      = (const float*)d_in[4];
  const float* W2      = (const float*)d_in[5];
  const float* b2      = (const float*)d_in[6];
  const float* Wo      = (const float*)d_in[7];
  const float* bo      = (const float*)d_in[8];
  float* out = (float*)d_out;

  float* ws   = (float*)d_ws;
  float* Wq   = ws;                        // 393216 floats
  float* Woq  = Wq + WQ_SZ;                //  81920
  float* WcT2 = Woq + WOQ_SZ;              // 131072
  float* b1p  = WcT2 + WCT_SZ;             //    512
  float* b2p  = b1p + 512;                 //    512
  // total ws use: ~2.4 MB (L2-resident)

  prep_kernel<<<(R5e + 255) / 256, 256, 0, stream>>>(
      W1, Wc, W2, Wo, b1, b2, Wq, Woq, WcT2, b1p, b2p);
  made_v22_kernel<<<Bn / Rn, 256, 0, stream>>>(context, WcT2, b1p, Wq, Woq,
                                               b2p, bo, eps, out);
}